// Round 1
// baseline (1136.634 us; speedup 1.0000x reference)
//
#include <hip/hip_runtime.h>
#include <math.h>

// SparseSoftmax: features (32,2048,2048) f32, OD (32,2048,2048) i32 (0/1).
// Rowwise masked softmax over last axis; masked-out entries -> 0; fully
// masked rows -> all zeros.
//
// One 256-thread block per row of 2048. Each thread owns 8 contiguous-by-
// vector elements via two float4/int4 loads -> registers. Single HBM pass.

#define ROW 2048
#define TPB 256
#define VEC 4            // float4
#define CHUNKS 2         // 2 x (256 threads * float4) = 2048 elements

__global__ __launch_bounds__(TPB) void sparse_softmax_kernel(
    const float4* __restrict__ feat,
    const int4* __restrict__ od,
    float4* __restrict__ out)
{
    const int tid = threadIdx.x;
    const long long row = blockIdx.x;
    const long long base = row * (long long)(ROW / VEC);  // in float4 units

    __shared__ float red[4];  // 4 waves per block

    // ---- load 8 elements/thread ----
    float4 fv[CHUNKS];
    int4   mv[CHUNKS];
#pragma unroll
    for (int j = 0; j < CHUNKS; ++j) {
        const long long idx = base + (long long)(j * TPB + tid);
        fv[j] = feat[idx];
        mv[j] = od[idx];
    }

    float vals[CHUNKS * VEC];
    bool  msk[CHUNKS * VEC];
#pragma unroll
    for (int j = 0; j < CHUNKS; ++j) {
        msk[j * 4 + 0] = (mv[j].x != 0);
        msk[j * 4 + 1] = (mv[j].y != 0);
        msk[j * 4 + 2] = (mv[j].z != 0);
        msk[j * 4 + 3] = (mv[j].w != 0);
        vals[j * 4 + 0] = msk[j * 4 + 0] ? fv[j].x : -INFINITY;
        vals[j * 4 + 1] = msk[j * 4 + 1] ? fv[j].y : -INFINITY;
        vals[j * 4 + 2] = msk[j * 4 + 2] ? fv[j].z : -INFINITY;
        vals[j * 4 + 3] = msk[j * 4 + 3] ? fv[j].w : -INFINITY;
    }

    // ---- block max ----
    float m = -INFINITY;
#pragma unroll
    for (int k = 0; k < CHUNKS * VEC; ++k) m = fmaxf(m, vals[k]);
#pragma unroll
    for (int off = 32; off >= 1; off >>= 1)
        m = fmaxf(m, __shfl_xor(m, off, 64));
    const int wid = tid >> 6;
    if ((tid & 63) == 0) red[wid] = m;
    __syncthreads();
    m = fmaxf(fmaxf(red[0], red[1]), fmaxf(red[2], red[3]));
    const float m_safe = isfinite(m) ? m : 0.0f;
    __syncthreads();  // protect red[] before reuse

    // ---- exp and block sum ----
    float p[CHUNKS * VEC];
    float s = 0.0f;
#pragma unroll
    for (int k = 0; k < CHUNKS * VEC; ++k) {
        p[k] = msk[k] ? expf(vals[k] - m_safe) : 0.0f;
        s += p[k];
    }
#pragma unroll
    for (int off = 32; off >= 1; off >>= 1)
        s += __shfl_xor(s, off, 64);
    if ((tid & 63) == 0) red[wid] = s;
    __syncthreads();
    s = (red[0] + red[1]) + (red[2] + red[3]);

    const float inv = (s > 0.0f) ? (1.0f / s) : 0.0f;

    // ---- write ----
#pragma unroll
    for (int j = 0; j < CHUNKS; ++j) {
        float4 o;
        o.x = p[j * 4 + 0] * inv;
        o.y = p[j * 4 + 1] * inv;
        o.z = p[j * 4 + 2] * inv;
        o.w = p[j * 4 + 3] * inv;
        out[base + (long long)(j * TPB + tid)] = o;
    }
}

extern "C" void kernel_launch(void* const* d_in, const int* in_sizes, int n_in,
                              void* d_out, int out_size, void* d_ws, size_t ws_size,
                              hipStream_t stream) {
    const float4* feat = (const float4*)d_in[0];
    const int4*   od   = (const int4*)d_in[1];
    float4*       out  = (float4*)d_out;

    const int rows = out_size / ROW;  // 32*2048 = 65536
    sparse_softmax_kernel<<<rows, TPB, 0, stream>>>(feat, od, out);
}